// Round 3
// baseline (125.557 us; speedup 1.0000x reference)
//
#include <hip/hip_runtime.h>
#include <hip/hip_bf16.h>

#define T_LEN   6000
#define F_DIM   80
#define NROWS   2560           // 32 * 80
#define CHUNK   256            // 64 lanes * 4 elems
#define NCHUNK  24             // 23 full chunks + 112-elem tail (112 = 28 lanes * 4)
#define DEPTH   8              // prefetch pipeline depth (8 KB in flight per wave)
#define FLOORV  1e-6f

typedef float vfloat4 __attribute__((ext_vector_type(4)));

// gfx950 hardware transcendentals (avoid glibc __exp2f/__log2f name collision)
__device__ __forceinline__ float hw_exp2(float x) { return __builtin_amdgcn_exp2f(x); }
__device__ __forceinline__ float hw_log2(float x) { return __builtin_amdgcn_logf(x); }

__device__ __forceinline__ vfloat4 load_chunk(const float* __restrict__ p, int k, int lane) {
    int t = k * CHUNK + lane * 4;
    if (t < T_LEN) {
        // row base = row*6000 floats = 24000 B (16B-aligned), t % 4 == 0 -> aligned
        return __builtin_nontemporal_load(reinterpret_cast<const vfloat4*>(p + t));
    }
    return (vfloat4){0.f, 0.f, 0.f, 0.f};
}

__global__ __launch_bounds__(64) void pcen_kernel(
    const float* __restrict__ x,
    const float* __restrict__ smooth,
    const float* __restrict__ alpha,
    const float* __restrict__ delta,
    const float* __restrict__ root,
    float* __restrict__ out)
{
    const int lane = threadIdx.x;      // block = 1 wave
    const int row  = blockIdx.x;       // 2560 blocks -> exactly 10 waves/CU, even
    const int f = row % F_DIM;

    // per-row parameters (wave-uniform)
    float s   = fminf(fmaxf(smooth[f], 0.f), 1.f);
    float c   = 1.f - s;
    float a   = fminf(alpha[f], 1.f);
    float d   = delta[f];
    float r   = fmaxf(root[f], 1.f);
    float inv_r = 1.f / r;
    float neg_a = -a;
    const bool use_sqrt = (inv_r == 0.5f);            // r == 2 -> v_sqrt path (wave-uniform)
    float droot = use_sqrt ? __builtin_sqrtf(d) : hw_exp2(inv_r * hw_log2(d));

    // powers of c
    const float c1 = c, c2 = c * c, c3 = c2 * c, c4 = c2 * c2;
    float q0 = c4;                 // c^(4*1)
    float q1 = q0 * q0;            // c^(4*2)
    float q2 = q1 * q1;            // c^(4*4)
    float q3 = q2 * q2;            // c^(4*8)
    float q4 = q3 * q3;            // c^(4*16)
    float q5 = q4 * q4;            // c^(4*32)
    float c256 = q5 * q5;          // c^256 : full-chunk decay
    // c^(4*lane); guard lane==0 against 0 * (-inf) when c==0
    float c4lane = (lane == 0) ? 1.0f : hw_exp2(4.0f * (float)lane * hw_log2(c));

    const float* __restrict__ px = x   + (size_t)row * T_LEN;
    float*       __restrict__ po = out + (size_t)row * T_LEN;

    // depth-8 software pipeline of chunk loads
    vfloat4 v[DEPTH];
#pragma unroll
    for (int i = 0; i < DEPTH; ++i) v[i] = load_chunk(px, i, lane);

    // carry = m at t=-1; setting it to x[0] makes m0 = c*x0 + s*x0 = x0 (ref: ema[0]=x[0])
    float carry = px[0];

#pragma unroll
    for (int k = 0; k < NCHUNK; ++k) {
        vfloat4 cur = v[k % DEPTH];
        if (k + DEPTH < NCHUNK) v[k % DEPTH] = load_chunk(px, k + DEPTH, lane);

        // local (per-lane) inclusive scan of 4 elements, as if m_in = 0
        float b0 = s * cur.x;
        float b1 = fmaf(c, b0, s * cur.y);
        float b2 = fmaf(c, b1, s * cur.z);
        float b3 = fmaf(c, b2, s * cur.w);

        // wave scan over lane carries. A-coefficients are the scalars q_k, so only
        // B needs combining: B_i = q_k * B_{i-2^k} + B_i  (lanes >= offset)
        float B = b3;
        {
            float Bu;
            Bu = __shfl_up(B, 1, 64);  if (lane >= 1)  B = fmaf(q0, Bu, B);
            Bu = __shfl_up(B, 2, 64);  if (lane >= 2)  B = fmaf(q1, Bu, B);
            Bu = __shfl_up(B, 4, 64);  if (lane >= 4)  B = fmaf(q2, Bu, B);
            Bu = __shfl_up(B, 8, 64);  if (lane >= 8)  B = fmaf(q3, Bu, B);
            Bu = __shfl_up(B, 16, 64); if (lane >= 16) B = fmaf(q4, Bu, B);
            Bu = __shfl_up(B, 32, 64); if (lane >= 32) B = fmaf(q5, Bu, B);
        }
        // exclusive prefix for this lane
        float Bex = __shfl_up(B, 1, 64);
        if (lane == 0) Bex = 0.f;
        float m_in = fmaf(c4lane, carry, Bex);

        // chunk carry update (do early so scheduler can overlap with pcen math)
        float B63 = __shfl(B, 63, 64);
        carry = fmaf(c256, carry, B63);

        // per-element EMA values
        float m[4];
        m[0] = fmaf(c1, m_in, b0);
        m[1] = fmaf(c2, m_in, b1);
        m[2] = fmaf(c3, m_in, b2);
        m[3] = fmaf(c4, m_in, b3);

        float xin[4] = {cur.x, cur.y, cur.z, cur.w};
        vfloat4 o;
        float ov[4];
#pragma unroll
        for (int j = 0; j < 4; ++j) {
            float g = hw_exp2(neg_a * hw_log2(m[j] + FLOORV));  // (FLOOR+ema)^(-a)
            float y = fmaf(xin[j], g, d);                        // >= d > 0
            float p = use_sqrt ? __builtin_sqrtf(y)
                               : hw_exp2(inv_r * hw_log2(y));
            ov[j] = p - droot;
        }
        o.x = ov[0]; o.y = ov[1]; o.z = ov[2]; o.w = ov[3];

        int t = k * CHUNK + lane * 4;
        if (t < T_LEN) {
            __builtin_nontemporal_store(o, reinterpret_cast<vfloat4*>(po + t));
        }
    }
}

extern "C" void kernel_launch(void* const* d_in, const int* in_sizes, int n_in,
                              void* d_out, int out_size, void* d_ws, size_t ws_size,
                              hipStream_t stream) {
    const float* x      = (const float*)d_in[0];
    const float* smooth = (const float*)d_in[1];
    const float* alpha  = (const float*)d_in[2];
    const float* delta  = (const float*)d_in[3];
    const float* root   = (const float*)d_in[4];
    float* out = (float*)d_out;

    dim3 grid(NROWS);   // one wave per (B,F) row, 2560 blocks -> exactly 10 waves/CU
    dim3 block(64);
    pcen_kernel<<<grid, block, 0, stream>>>(x, smooth, alpha, delta, root, out);
}

// Round 4
// 117.308 us; speedup vs baseline: 1.0703x; 1.0703x over previous
//
#include <hip/hip_runtime.h>
#include <hip/hip_bf16.h>

#define T_LEN    6000
#define F_DIM    80
#define NROWS    2560          // 32 * 80
#define SEG_LEN  3000          // 2 segments per row
#define NSEG     2
#define WARM     512           // lookback warm-up (c^512 ~ 8e-10, negligible)
#define CHUNK    256           // 64 lanes * 4 elems
#define NCHUNK   12            // ceil(3000/256): 11 full + 184-elem tail
#define DEPTH    4             // prefetch pipeline depth (4 KB in flight per wave)
#define FLOORV   1e-6f

typedef float vfloat4 __attribute__((ext_vector_type(4)));

// gfx950 hardware transcendentals (avoid glibc __exp2f/__log2f name collision)
__device__ __forceinline__ float hw_exp2(float x) { return __builtin_amdgcn_exp2f(x); }
__device__ __forceinline__ float hw_log2(float x) { return __builtin_amdgcn_logf(x); }

__device__ __forceinline__ vfloat4 load_chunk(const float* __restrict__ p, int t) {
    if (t < T_LEN) {
        // row base and seg offsets are 16B-aligned, t % 4 == 0 -> aligned float4
        return *reinterpret_cast<const vfloat4*>(p + t);
    }
    return (vfloat4){0.f, 0.f, 0.f, 0.f};
}

// inclusive wave scan of per-lane carries b3 with scalar pair-coefficients q_k
__device__ __forceinline__ float wave_scan(float b3, int lane,
                                           float q0, float q1, float q2,
                                           float q3, float q4, float q5) {
    float B = b3, Bu;
    Bu = __shfl_up(B, 1, 64);  if (lane >= 1)  B = fmaf(q0, Bu, B);
    Bu = __shfl_up(B, 2, 64);  if (lane >= 2)  B = fmaf(q1, Bu, B);
    Bu = __shfl_up(B, 4, 64);  if (lane >= 4)  B = fmaf(q2, Bu, B);
    Bu = __shfl_up(B, 8, 64);  if (lane >= 8)  B = fmaf(q3, Bu, B);
    Bu = __shfl_up(B, 16, 64); if (lane >= 16) B = fmaf(q4, Bu, B);
    Bu = __shfl_up(B, 32, 64); if (lane >= 32) B = fmaf(q5, Bu, B);
    return B;
}

__global__ __launch_bounds__(256, 6) void pcen_kernel(
    const float* __restrict__ x,
    const float* __restrict__ smooth,
    const float* __restrict__ alpha,
    const float* __restrict__ delta,
    const float* __restrict__ root,
    float* __restrict__ out)
{
    const int lane = threadIdx.x & 63;
    const int wave = threadIdx.x >> 6;
    const int gid  = blockIdx.x * 4 + wave;   // 0..5119 wave tasks
    const int row  = gid >> 1;                // (B,F) row
    const int seg  = gid & 1;                 // half of the row
    const int f    = row % F_DIM;

    // per-row parameters (wave-uniform)
    float s   = fminf(fmaxf(smooth[f], 0.f), 1.f);
    float c   = 1.f - s;
    float a   = fminf(alpha[f], 1.f);
    float d   = delta[f];
    float r   = fmaxf(root[f], 1.f);
    float inv_r = 1.f / r;
    float neg_a = -a;
    const bool use_sqrt = (inv_r == 0.5f);    // r == 2 -> v_sqrt path (wave-uniform)
    float droot = use_sqrt ? __builtin_sqrtf(d) : hw_exp2(inv_r * hw_log2(d));

    // powers of c
    const float c1 = c, c2 = c * c, c3 = c2 * c, c4 = c2 * c2;
    float q0 = c4;                 // c^(4*1)
    float q1 = q0 * q0;            // c^(4*2)
    float q2 = q1 * q1;            // c^(4*4)
    float q3 = q2 * q2;            // c^(4*8)
    float q4 = q3 * q3;            // c^(4*16)
    float q5 = q4 * q4;            // c^(4*32)
    float c256 = q5 * q5;          // c^256 : full-chunk decay
    // c^(4*lane); guard lane==0 against 0 * (-inf) when c==0
    float c4lane = (lane == 0) ? 1.0f : hw_exp2(4.0f * (float)lane * hw_log2(c));

    const int seg_start = seg * SEG_LEN;
    const int store_end = seg_start + SEG_LEN;

    const float* __restrict__ px = x   + (size_t)row * T_LEN;
    float*       __restrict__ po = out + (size_t)row * T_LEN;

    // ---- issue all leading loads first (warm-up + DEPTH main prefetch) ----
    vfloat4 wv0, wv1;
    if (seg) {
        const float* pw = px + seg_start - WARM;           // 16B-aligned
        wv0 = *reinterpret_cast<const vfloat4*>(pw + lane * 4);
        wv1 = *reinterpret_cast<const vfloat4*>(pw + CHUNK + lane * 4);
    }
    vfloat4 v[DEPTH];
#pragma unroll
    for (int i = 0; i < DEPTH; ++i)
        v[i] = load_chunk(px, seg_start + i * CHUNK + lane * 4);

    // ---- carry init ----
    float carry;
    if (seg) {
        // 512-step lookback: start from 0, error = c^512 * m_true ~ 1e-9
        carry = 0.f;
#pragma unroll
        for (int w = 0; w < 2; ++w) {
            vfloat4 cw = (w == 0) ? wv0 : wv1;
            float b0 = s * cw.x;
            float b1 = fmaf(c, b0, s * cw.y);
            float b2 = fmaf(c, b1, s * cw.z);
            float b3 = fmaf(c, b2, s * cw.w);
            float B = wave_scan(b3, lane, q0, q1, q2, q3, q4, q5);
            float B63 = __shfl(B, 63, 64);
            carry = fmaf(c256, carry, B63);
        }
    } else {
        // carry = m at t=-1; x[0] makes m0 = c*x0 + s*x0 = x0 (ref: ema[0]=x[0])
        carry = px[0];
    }

    // ---- main loop over 12 chunks of this segment ----
#pragma unroll
    for (int k = 0; k < NCHUNK; ++k) {
        vfloat4 cur = v[k % DEPTH];
        if (k + DEPTH < NCHUNK)
            v[k % DEPTH] = load_chunk(px, seg_start + (k + DEPTH) * CHUNK + lane * 4);

        // local (per-lane) inclusive scan of 4 elements, as if m_in = 0
        float b0 = s * cur.x;
        float b1 = fmaf(c, b0, s * cur.y);
        float b2 = fmaf(c, b1, s * cur.z);
        float b3 = fmaf(c, b2, s * cur.w);

        float B = wave_scan(b3, lane, q0, q1, q2, q3, q4, q5);

        // exclusive prefix for this lane
        float Bex = __shfl_up(B, 1, 64);
        if (lane == 0) Bex = 0.f;
        float m_in = fmaf(c4lane, carry, Bex);

        // chunk carry update (early, so next chunk's scan can overlap pcen math)
        float B63 = __shfl(B, 63, 64);
        carry = fmaf(c256, carry, B63);

        // per-element EMA values
        float m[4];
        m[0] = fmaf(c1, m_in, b0);
        m[1] = fmaf(c2, m_in, b1);
        m[2] = fmaf(c3, m_in, b2);
        m[3] = fmaf(c4, m_in, b3);

        float xin[4] = {cur.x, cur.y, cur.z, cur.w};
        float ov[4];
#pragma unroll
        for (int j = 0; j < 4; ++j) {
            float g = hw_exp2(neg_a * hw_log2(m[j] + FLOORV));  // (FLOOR+ema)^(-a)
            float y = fmaf(xin[j], g, d);                        // >= d > 0
            float p = use_sqrt ? __builtin_sqrtf(y)
                               : hw_exp2(inv_r * hw_log2(y));
            ov[j] = p - droot;
        }
        vfloat4 o = (vfloat4){ov[0], ov[1], ov[2], ov[3]};

        int t = seg_start + k * CHUNK + lane * 4;
        if (t < store_end) {
            *reinterpret_cast<vfloat4*>(po + t) = o;
        }
    }
}

extern "C" void kernel_launch(void* const* d_in, const int* in_sizes, int n_in,
                              void* d_out, int out_size, void* d_ws, size_t ws_size,
                              hipStream_t stream) {
    const float* x      = (const float*)d_in[0];
    const float* smooth = (const float*)d_in[1];
    const float* alpha  = (const float*)d_in[2];
    const float* delta  = (const float*)d_in[3];
    const float* root   = (const float*)d_in[4];
    float* out = (float*)d_out;

    // 2560 rows x 2 segments = 5120 wave-tasks; 4 waves/block -> 1280 blocks
    dim3 grid(NROWS * NSEG / 4);
    dim3 block(256);
    pcen_kernel<<<grid, block, 0, stream>>>(x, smooth, alpha, delta, root, out);
}